// Round 6
// baseline (791.118 us; speedup 1.0000x reference)
//
#include <hip/hip_runtime.h>
#include <hip/hip_bf16.h>
#include <math.h>

#define L_DIM 4096
#define H_DIM 512
#define B_DIM 8
#define SEG 1024

typedef __attribute__((ext_vector_type(8))) short short8;
typedef __attribute__((ext_vector_type(4))) float floatx4;

__device__ __forceinline__ unsigned f2bf(float f) {
    unsigned x = __float_as_uint(f);
    return (x + 0x7fffu + ((x >> 16) & 1u)) >> 16;   // RNE, finite inputs only
}

// ---------------------------------------------------------------------------
// Stage 1 (MFMA): causal Toeplitz conv + D-skip + exact GELU.
// Round-13: SEG 2048 -> 1024. Round-12 proved TLP is the lever (157->125us
// purely from 12->15 waves/CU); the only remaining occupancy blocker was
// the us[] window (33.7KB at SEG 2048 -> LDS 50.7KB -> 3 blocks/CU).
// SEG 1024 shrinks us to 17.3KB -> LDS 33.9KB -> 4 blocks/CU = 32 waves/CU
// (hard max), grid 1024 blocks = exactly 4/CU (no tail). The m0 grid is
// stride-32; [-32,992] u [1024,2016] covers exactly the old [-32,2016] set,
// so the iteration space is identical -- only ms/mstart/segmax scale.
// VGPR must stay <=64 for 8 waves/SIMD (round-12 body compiled to 40).
// ---------------------------------------------------------------------------
__global__ __launch_bounds__(512, 8) void conv_gelu_mfma(
    const float* __restrict__ u,    // (B,H,L) fp32
    const float* __restrict__ kk,   // (C=1,H,L) fp32
    const float* __restrict__ Dp,   // (H) fp32
    unsigned short* __restrict__ g, // (B,H,L) bf16 out (workspace)
    const float* __restrict__ W,    // (H,H) fp32
    unsigned short* __restrict__ Wb)// (H,H) bf16 out (workspace tail), may be null
{
    __shared__ __align__(16) unsigned short kA[4144];
    __shared__ __align__(16) unsigned short kB[4144];
    __shared__ __align__(16) unsigned short us[8][1080];

    const int h   = blockIdx.x;
    const int Lb  = blockIdx.y << 11;        // l-chunk base (2048 per block)
    const int tid = threadIdx.x;
    const int lane = tid & 63;
    const int w   = tid >> 6;                // wave id 0..7
    const int i   = lane & 15;               // A-row / C-col index
    const int q   = lane >> 4;               // quad
    const int b   = i & 7;                   // batch   (C-col decode)
    const int s   = i >> 3;                  // l-tile  (C-col decode)

    // one-time W fp32 -> bf16 conversion (coalesced, one row per h-block)
    if (Wb != nullptr && blockIdx.y == 0) {
        const float* wsrc = W + (size_t)h * H_DIM;
        unsigned short* wdst = Wb + (size_t)h * H_DIM;
        wdst[tid] = (unsigned short)f2bf(wsrc[tid]);
    }

    const float* kh = kk + (size_t)h * L_DIM;

    for (int p = tid; p < 4144; p += 512) {
        int t1 = L_DIM + 15 - p;
        int t2 = L_DIM + 14 - p;
        float v1 = (t1 >= 0 && t1 < L_DIM) ? kh[t1] : 0.0f;
        float v2 = (t2 >= 0 && t2 < L_DIM) ? kh[t2] : 0.0f;
        kA[p] = (unsigned short)f2bf(v1);
        kB[p] = (unsigned short)f2bf(v2);
    }

    floatx4 acc[8];
    #pragma unroll
    for (int t = 0; t < 8; t++) acc[t] = (floatx4){0.f, 0.f, 0.f, 0.f};

    const char* kbase = (const char*)((i & 1) ? kA : kB);
    const int aconst = 2 * (L_DIM + ((i & 1) ? 15 : 14) - i + 8 * q);
    const int basew = Lb + 32 * w;           // l0(t) = basew + 256*t

    union AFrag { int x[4]; short8 v; };

    for (int seg = 0; seg < 4; seg++) {
        const int ms = seg * SEG;
        const int mstart = (seg == 0) ? -32 : ms;
        const int segmax = ms + SEG - 32;
        if (seg >= 1) {
            // max m0 any wave needs = basew_max + 1792 = Lb + 2016
            if (Lb + 2016 < ms) break;       // uniform per block
            __syncthreads();                 // protect us[] until prev compute done
        }
        for (int e = tid * 4; e < SEG + 48; e += 2048) {
            int m = ms - 32 + e;
            #pragma unroll
            for (int bb = 0; bb < 8; bb++) {
                float4 v = make_float4(0.f, 0.f, 0.f, 0.f);
                if (m >= 0 && m < L_DIM)
                    v = *(const float4*)(u + ((size_t)bb * H_DIM + h) * L_DIM + m);
                unsigned lo = f2bf(v.x) | (f2bf(v.y) << 16);
                unsigned hi = f2bf(v.z) | (f2bf(v.w) << 16);
                *(uint2*)&us[bb][e] = make_uint2(lo, hi);
            }
        }
        __syncthreads();

        const char* bbase = (const char*)&us[b][0] + 2 * (32 - ms + 16 * s + 8 * q);
        const char* ab = kbase + aconst;     // A-frag address at dd = 0

        for (int c = 0; c < 8; c++) {
            const int c32 = 32 * c;
            const int rel = basew - c32;
            // m0(j) = rel - 256*j must lie in [mstart, segmax]
            const int j_hi = (rel - mstart) >> 8;            // floor div
            int j_lo = (rel - segmax + 255) >> 8;            // ceil div
            if (j_lo < -7) j_lo = -7;                        // t<=7 bound
            if (j_hi < j_lo) continue;
            const int n = j_hi - j_lo + 1;

            AFrag Wd[8];
            // preload slots d=1..7: sigma = j_hi + d (slots with dd out of the
            // used band are loaded-but-unused; dd<0 zero-guarded)
            #pragma unroll
            for (int d = 1; d < 8; d++) {
                const int dd = c32 + (j_hi + d) * 256;
                if (dd >= 0) {
                    const int* ap = (const int*)(ab - 2 * dd);
                    Wd[d].x[0] = ap[0]; Wd[d].x[1] = ap[1];
                    Wd[d].x[2] = ap[2]; Wd[d].x[3] = ap[3];
                } else {
                    Wd[d].x[0] = 0; Wd[d].x[1] = 0; Wd[d].x[2] = 0; Wd[d].x[3] = 0;
                }
            }

            const char* aab = ab - 2 * c32 - 512 * j_hi;     // +512*jj -> frag at j=j_hi-jj
            const char* bb0 = bbase + 2 * (rel - 256 * j_hi);// +512*jj -> B at m0(j)

            for (int jb = 0; jb < n; jb += 8) {
                #pragma unroll
                for (int k = 0; k < 8; k++) {
                    const int jj = jb + k;
                    if (jj < n) {
                        const int dd0 = c32 + (j_hi - jj) * 256;
                        AFrag nf;
                        if (dd0 >= 0) {
                            const int* ap = (const int*)(aab + 512 * jj);
                            nf.x[0] = ap[0]; nf.x[1] = ap[1];
                            nf.x[2] = ap[2]; nf.x[3] = ap[3];
                        } else {
                            // non-causal diagonal: zero frag -> MFMA adds 0
                            nf.x[0] = 0; nf.x[1] = 0; nf.x[2] = 0; nf.x[3] = 0;
                        }
                        Wd[(8 - k) & 7] = nf;                // slot (-jj)&7, static
                        short8 bf = *(const short8*)(bb0 + 512 * jj);
                        #pragma unroll
                        for (int t = 0; t < 8; t++)
                            acc[t] = __builtin_amdgcn_mfma_f32_16x16x32_bf16(
                                Wd[(t - k) & 7].v, bf, acc[t], 0, 0, 0);
                    }
                }
            }
        }
    }

    const float Dh = Dp[h];
    #pragma unroll
    for (int t = 0; t < 8; t++) {
        const int l0 = Lb + 32 * w + 256 * t;
        const int lb2 = l0 + 16 * s + 4 * q;          // C/D: row = 4q + r, col = (b,s)
        const size_t off = ((size_t)b * H_DIM + h) * L_DIM + lb2;
        float4 uv = *(const float4*)(u + off);
        float y0 = acc[t][0] + uv.x * Dh;
        float y1 = acc[t][1] + uv.y * Dh;
        float y2 = acc[t][2] + uv.z * Dh;
        float y3 = acc[t][3] + uv.w * Dh;
        const float c = 0.70710678118654752f;
        float g0 = 0.5f * y0 * (1.0f + erff(y0 * c));
        float g1 = 0.5f * y1 * (1.0f + erff(y1 * c));
        float g2 = 0.5f * y2 * (1.0f + erff(y2 * c));
        float g3 = 0.5f * y3 * (1.0f + erff(y3 * c));
        unsigned lo = f2bf(g0) | (f2bf(g1) << 16);
        unsigned hi = f2bf(g2) | (f2bf(g3) << 16);
        *(uint2*)(g + off) = make_uint2(lo, hi);
    }
}

// ---------------------------------------------------------------------------
// Stage 2 (MFMA v3): out[b,d,l] = sum_c W[d,c]*g[b,c,l] + bias[d], fp32 out.
// Round-13: (1) REVERT the async split (round-12 regressed ~110->125us --
// the fence + extra barrier pair cost more than the latency it hid).
// (2) gs2 stride 36->40: af-read word-bank was 4(n+q)%32 -> 8 lanes/bank-
// quad = 2.94x slowdown on the 16 af reads/iter; stride 40 gives disjoint
// 4-lane groups (1.58x) and keeps 16B alignment. (3) 512-thread blocks on
// the same 128l x 256d tile: wave = 64l x 64d (wh=w&1 l-half, wd=w>>1
// d-quarter), acc 4x4 = 64 VGPR -> 4 waves/SIMD legal; LDS 59.4KB -> 2
// blocks/CU -> 16 waves/CU (was 8). Staging split by hi = tid>>8.
// ---------------------------------------------------------------------------
template <bool PREW>
__global__ __launch_bounds__(512, 4) void pointwise_mfma(
    const unsigned short* __restrict__ g,  // (B,H,L) bf16 (workspace)
    const unsigned short* __restrict__ Wb, // (H,H) bf16 (workspace tail) if PREW
    const float* __restrict__ W,           // (H,H) fp32 row-major [d][c]
    const float* __restrict__ bias,        // (H) fp32
    float* __restrict__ out)               // (B,H,L) fp32
{
    __shared__ __align__(16) unsigned gs2[128 * 40];        // 20480 B
    __shared__ __align__(16) unsigned short ws[256 * 76];   // 38912 B

    const int tid = threadIdx.x;
    const int l0 = blockIdx.x * 128;
    const int d0 = blockIdx.y * 256;
    const int bz = blockIdx.z;
    const int w  = tid >> 6;
    const int lane = tid & 63;
    const int n  = lane & 15;      // MFMA row/col lane index
    const int q  = lane >> 4;      // quad
    const int wh = w & 1;          // l-half 0..1
    const int wd = w >> 1;         // d-quarter 0..3

    const int p   = tid & 31;      // c-pair column for g staging
    const int oct = (tid >> 5) & 7;// l-16-group 0..7 for g staging
    const int hi  = tid >> 8;      // staging split 0..1

    const int quarter = tid & 3;   // c-quarter for W staging
    const int rb      = (tid >> 2) & 63; // d-row base 0..63 for W staging

    floatx4 acc[4][4];
    #pragma unroll
    for (int mt = 0; mt < 4; mt++)
        #pragma unroll
        for (int nt = 0; nt < 4; nt++) acc[mt][nt] = (floatx4){0.f, 0.f, 0.f, 0.f};

    for (int c0 = 0; c0 < H_DIM; c0 += 64) {
        // ---- stage g tile (transpose-pack): rows c0+2p/+1, l = l0+16*oct+8*hi+0..7
        {
            const unsigned short* gp = g + ((size_t)bz * H_DIM + c0 + 2 * p) * L_DIM
                                         + l0 + 16 * oct + 8 * hi;
            uint4 va = *(const uint4*)gp;
            uint4 vb = *(const uint4*)(gp + L_DIM);
            const unsigned* ua = (const unsigned*)&va;
            const unsigned* ub = (const unsigned*)&vb;
            #pragma unroll
            for (int e = 0; e < 4; e++) {
                unsigned w0 = (ua[e] & 0xFFFFu) | (ub[e] << 16);        // l even
                unsigned w1 = (ua[e] >> 16) | (ub[e] & 0xFFFF0000u);    // l odd
                const int lrow = 16 * oct + 8 * hi + 2 * e;
                gs2[lrow * 40 + p] = w0;
                gs2[(lrow + 1) * 40 + p] = w1;
            }
        }
        // ---- stage W tile: rows rb + 64*(2*hi+g2), c = 16*quarter..+15
        if (PREW) {
            #pragma unroll
            for (int g2 = 0; g2 < 2; g2++) {
                const int row = rb + 64 * (2 * hi + g2);
                const unsigned short* wp = Wb + (size_t)(d0 + row) * H_DIM + c0 + 16 * quarter;
                uint4 w0 = ((const uint4*)wp)[0];
                uint4 w1 = ((const uint4*)wp)[1];
                *(uint4*)&ws[row * 76 + 16 * quarter]     = w0;
                *(uint4*)&ws[row * 76 + 16 * quarter + 8] = w1;
            }
        } else {
            #pragma unroll
            for (int g2 = 0; g2 < 2; g2++) {
                const int row = rb + 64 * (2 * hi + g2);
                const float* wp = W + (size_t)(d0 + row) * H_DIM + c0 + 16 * quarter;
                float4 f0 = ((const float4*)wp)[0];
                float4 f1 = ((const float4*)wp)[1];
                float4 f2 = ((const float4*)wp)[2];
                float4 f3 = ((const float4*)wp)[3];
                unsigned o0 = f2bf(f0.x) | (f2bf(f0.y) << 16);
                unsigned o1 = f2bf(f0.z) | (f2bf(f0.w) << 16);
                unsigned o2 = f2bf(f1.x) | (f2bf(f1.y) << 16);
                unsigned o3 = f2bf(f1.z) | (f2bf(f1.w) << 16);
                unsigned o4 = f2bf(f2.x) | (f2bf(f2.y) << 16);
                unsigned o5 = f2bf(f2.z) | (f2bf(f2.w) << 16);
                unsigned o6 = f2bf(f3.x) | (f2bf(f3.y) << 16);
                unsigned o7 = f2bf(f3.z) | (f2bf(f3.w) << 16);
                *(uint4*)&ws[row * 76 + 16 * quarter]     = make_uint4(o0, o1, o2, o3);
                *(uint4*)&ws[row * 76 + 16 * quarter + 8] = make_uint4(o4, o5, o6, o7);
            }
        }
        __syncthreads();

        // ---- compute: 2 K-steps of 32; per wave 4 mt x 4 nt MFMAs per step
        #pragma unroll
        for (int ks = 0; ks < 2; ks++) {
            short8 bfr[4];
            #pragma unroll
            for (int nt = 0; nt < 4; nt++)
                bfr[nt] = *(const short8*)&ws[(64 * wd + 16 * nt + n) * 76 + 32 * ks + 8 * q];
            #pragma unroll
            for (int mt = 0; mt < 4; mt++) {
                union { uint4 u4; short8 v; } af;
                af.u4 = *(const uint4*)&gs2[(64 * wh + 16 * mt + n) * 40 + 16 * ks + 4 * q];
                #pragma unroll
                for (int nt = 0; nt < 4; nt++)
                    acc[mt][nt] = __builtin_amdgcn_mfma_f32_16x16x32_bf16(af.v, bfr[nt], acc[mt][nt], 0, 0, 0);
            }
        }
        __syncthreads();
    }

    // ---- epilogue: bias + coalesced float4 stores (4 consecutive l per lane)
    #pragma unroll
    for (int nt = 0; nt < 4; nt++) {
        const int d = d0 + 64 * wd + 16 * nt + n;
        const float bb = bias[d];
        float* obase = out + ((size_t)bz * H_DIM + d) * L_DIM + l0 + 64 * wh + 4 * q;
        #pragma unroll
        for (int mt = 0; mt < 4; mt++) {
            float4 r = make_float4(acc[mt][nt][0] + bb, acc[mt][nt][1] + bb,
                                   acc[mt][nt][2] + bb, acc[mt][nt][3] + bb);
            *(float4*)(obase + 16 * mt) = r;
        }
    }
}

extern "C" void kernel_launch(void* const* d_in, const int* in_sizes, int n_in,
                              void* d_out, int out_size, void* d_ws, size_t ws_size,
                              hipStream_t stream) {
    const float* u    = (const float*)d_in[0]; // (B,H,L)
    const float* k    = (const float*)d_in[1]; // (C,H,L) C=1
    const float* D    = (const float*)d_in[2]; // (C,H)
    const float* W    = (const float*)d_in[3]; // (H,C*H)
    const float* bias = (const float*)d_in[4]; // (H)
    float* out = (float*)d_out;
    unsigned short* g = (unsigned short*)d_ws;  // (B,H,L) bf16 intermediate, 32 MiB

    const size_t g_bytes = (size_t)B_DIM * H_DIM * L_DIM * sizeof(unsigned short); // 32 MiB
    const size_t w_bytes = (size_t)H_DIM * H_DIM * sizeof(unsigned short);         // 512 KiB
    const bool prew = ws_size >= g_bytes + w_bytes;
    unsigned short* Wb = prew ? (unsigned short*)((char*)d_ws + g_bytes) : nullptr;

    conv_gelu_mfma<<<dim3(H_DIM, L_DIM / 2048), 512, 0, stream>>>(u, k, D, g, W, Wb);
    if (prew)
        pointwise_mfma<true><<<dim3(L_DIM / 128, H_DIM / 256, B_DIM), 512, 0, stream>>>(g, Wb, W, bias, out);
    else
        pointwise_mfma<false><<<dim3(L_DIM / 128, H_DIM / 256, B_DIM), 512, 0, stream>>>(g, nullptr, W, bias, out);
}

// Round 7
// 256.352 us; speedup vs baseline: 3.0861x; 3.0861x over previous
//
#include <hip/hip_runtime.h>
#include <hip/hip_bf16.h>
#include <math.h>

#define L_DIM 4096
#define H_DIM 512
#define B_DIM 8
#define SEG 1024

typedef __attribute__((ext_vector_type(8))) short short8;
typedef __attribute__((ext_vector_type(4))) float floatx4;

__device__ __forceinline__ unsigned f2bf(float f) {
    unsigned x = __float_as_uint(f);
    return (x + 0x7fffu + ((x >> 16) & 1u)) >> 16;   // RNE, finite inputs only
}

// ---------------------------------------------------------------------------
// Stage 1 (MFMA): causal Toeplitz conv + D-skip + exact GELU.
// Round-14: T=4 / window-4. Round-6 spilled because launch_bounds(512,8)
// caps the UNIFIED VGPR+AGPR budget at 64 and the T=8 body needs ~72
// (acc[8]=32 AGPR + Wd[8]=32 VGPR + addr) -> 1.1GB scratch traffic.
// Fix: halve per-wave state, not occupancy. t-count 4 (acc 16) + window
// depth 4 (Wd 16) => ~56 regs total, fits 8 waves/SIMD with no spill.
// l-chunk 1024 (8 waves x bases 0..224 x t in [0,4) stride 256 tile it
// exactly); SEG 1024 -> LDS 33.9KB -> 4 blocks/CU -> 32 waves/CU (max).
// Window algebra is the verified T=8 form with 8->4: slot (t-k)&3,
// preload d=1..3 at sigma=j_hi+d, j_lo clamp -3. dd_max = Lb+1024 <= 4096,
// same kA zero-pad bound as round-5 (HW-verified). LDS reads per MFMA
// double (amortize over 4 not 8) -> LDS pipe ~50us becomes the pole, but
// 32 waves/CU hides it.
// ---------------------------------------------------------------------------
__global__ __launch_bounds__(512, 8) void conv_gelu_mfma(
    const float* __restrict__ u,    // (B,H,L) fp32
    const float* __restrict__ kk,   // (C=1,H,L) fp32
    const float* __restrict__ Dp,   // (H) fp32
    unsigned short* __restrict__ g, // (B,H,L) bf16 out (workspace)
    const float* __restrict__ W,    // (H,H) fp32
    unsigned short* __restrict__ Wb)// (H,H) bf16 out (workspace tail), may be null
{
    __shared__ __align__(16) unsigned short kA[4144];
    __shared__ __align__(16) unsigned short kB[4144];
    __shared__ __align__(16) unsigned short us[8][1080];

    const int h   = blockIdx.x;
    const int Lb  = blockIdx.y << 10;        // l-chunk base (1024 per block)
    const int tid = threadIdx.x;
    const int lane = tid & 63;
    const int w   = tid >> 6;                // wave id 0..7
    const int i   = lane & 15;               // A-row / C-col index
    const int q   = lane >> 4;               // quad
    const int b   = i & 7;                   // batch   (C-col decode)
    const int s   = i >> 3;                  // l-tile  (C-col decode)

    // one-time W fp32 -> bf16 conversion (coalesced, one row per h-block)
    if (Wb != nullptr && blockIdx.y == 0) {
        const float* wsrc = W + (size_t)h * H_DIM;
        unsigned short* wdst = Wb + (size_t)h * H_DIM;
        wdst[tid] = (unsigned short)f2bf(wsrc[tid]);
    }

    const float* kh = kk + (size_t)h * L_DIM;

    for (int p = tid; p < 4144; p += 512) {
        int t1 = L_DIM + 15 - p;
        int t2 = L_DIM + 14 - p;
        float v1 = (t1 >= 0 && t1 < L_DIM) ? kh[t1] : 0.0f;
        float v2 = (t2 >= 0 && t2 < L_DIM) ? kh[t2] : 0.0f;
        kA[p] = (unsigned short)f2bf(v1);
        kB[p] = (unsigned short)f2bf(v2);
    }

    floatx4 acc[4];
    #pragma unroll
    for (int t = 0; t < 4; t++) acc[t] = (floatx4){0.f, 0.f, 0.f, 0.f};

    const char* kbase = (const char*)((i & 1) ? kA : kB);
    const int aconst = 2 * (L_DIM + ((i & 1) ? 15 : 14) - i + 8 * q);
    const int basew = Lb + 32 * w;           // l0(t) = basew + 256*t, t in [0,4)

    union AFrag { int x[4]; short8 v; };

    for (int seg = 0; seg < 4; seg++) {
        const int ms = seg * SEG;
        const int mstart = (seg == 0) ? -32 : ms;
        const int segmax = ms + SEG - 32;
        if (seg >= 1) {
            // max m0 any wave needs = basew_max + 768 = Lb + 992
            if (Lb + 992 < ms) break;        // uniform per block
            __syncthreads();                 // protect us[] until prev compute done
        }
        for (int e = tid * 4; e < SEG + 48; e += 2048) {
            int m = ms - 32 + e;
            #pragma unroll
            for (int bb = 0; bb < 8; bb++) {
                float4 v = make_float4(0.f, 0.f, 0.f, 0.f);
                if (m >= 0 && m < L_DIM)
                    v = *(const float4*)(u + ((size_t)bb * H_DIM + h) * L_DIM + m);
                unsigned lo = f2bf(v.x) | (f2bf(v.y) << 16);
                unsigned hi = f2bf(v.z) | (f2bf(v.w) << 16);
                *(uint2*)&us[bb][e] = make_uint2(lo, hi);
            }
        }
        __syncthreads();

        const char* bbase = (const char*)&us[b][0] + 2 * (32 - ms + 16 * s + 8 * q);
        const char* ab = kbase + aconst;     // A-frag address at dd = 0

        for (int c = 0; c < 8; c++) {
            const int c32 = 32 * c;
            const int rel = basew - c32;
            // m0(j) = rel - 256*j must lie in [mstart, segmax]
            const int j_hi = (rel - mstart) >> 8;            // floor div
            int j_lo = (rel - segmax + 255) >> 8;            // ceil div
            if (j_lo < -3) j_lo = -3;                        // t<=3 bound
            if (j_hi < j_lo) continue;
            const int n = j_hi - j_lo + 1;

            AFrag Wd[4];
            // preload slots d=1..3: sigma = j_hi + d (dd<0 zero-guarded)
            #pragma unroll
            for (int d = 1; d < 4; d++) {
                const int dd = c32 + (j_hi + d) * 256;
                if (dd >= 0) {
                    const int* ap = (const int*)(ab - 2 * dd);
                    Wd[d].x[0] = ap[0]; Wd[d].x[1] = ap[1];
                    Wd[d].x[2] = ap[2]; Wd[d].x[3] = ap[3];
                } else {
                    Wd[d].x[0] = 0; Wd[d].x[1] = 0; Wd[d].x[2] = 0; Wd[d].x[3] = 0;
                }
            }

            const char* aab = ab - 2 * c32 - 512 * j_hi;     // +512*jj -> frag at j=j_hi-jj
            const char* bb0 = bbase + 2 * (rel - 256 * j_hi);// +512*jj -> B at m0(j)

            for (int jb = 0; jb < n; jb += 4) {
                #pragma unroll
                for (int k = 0; k < 4; k++) {
                    const int jj = jb + k;
                    if (jj < n) {
                        const int dd0 = c32 + (j_hi - jj) * 256;
                        AFrag nf;
                        if (dd0 >= 0) {
                            const int* ap = (const int*)(aab + 512 * jj);
                            nf.x[0] = ap[0]; nf.x[1] = ap[1];
                            nf.x[2] = ap[2]; nf.x[3] = ap[3];
                        } else {
                            // non-causal diagonal: zero frag -> MFMA adds 0
                            nf.x[0] = 0; nf.x[1] = 0; nf.x[2] = 0; nf.x[3] = 0;
                        }
                        Wd[(4 - k) & 3] = nf;                // slot (-jj)&3, static
                        short8 bf = *(const short8*)(bb0 + 512 * jj);
                        #pragma unroll
                        for (int t = 0; t < 4; t++)
                            acc[t] = __builtin_amdgcn_mfma_f32_16x16x32_bf16(
                                Wd[(t - k) & 3].v, bf, acc[t], 0, 0, 0);
                    }
                }
            }
        }
    }

    const float Dh = Dp[h];
    #pragma unroll
    for (int t = 0; t < 4; t++) {
        const int l0 = Lb + 32 * w + 256 * t;
        const int lb2 = l0 + 16 * s + 4 * q;          // C/D: row = 4q + r, col = (b,s)
        const size_t off = ((size_t)b * H_DIM + h) * L_DIM + lb2;
        float4 uv = *(const float4*)(u + off);
        float y0 = acc[t][0] + uv.x * Dh;
        float y1 = acc[t][1] + uv.y * Dh;
        float y2 = acc[t][2] + uv.z * Dh;
        float y3 = acc[t][3] + uv.w * Dh;
        const float c = 0.70710678118654752f;
        float g0 = 0.5f * y0 * (1.0f + erff(y0 * c));
        float g1 = 0.5f * y1 * (1.0f + erff(y1 * c));
        float g2 = 0.5f * y2 * (1.0f + erff(y2 * c));
        float g3 = 0.5f * y3 * (1.0f + erff(y3 * c));
        unsigned lo = f2bf(g0) | (f2bf(g1) << 16);
        unsigned hi = f2bf(g2) | (f2bf(g3) << 16);
        *(uint2*)(g + off) = make_uint2(lo, hi);
    }
}

// ---------------------------------------------------------------------------
// Stage 2 (MFMA v3): out[b,d,l] = sum_c W[d,c]*g[b,c,l] + bias[d], fp32 out.
// UNCHANGED from round-6 (verified ~104us): 512-thread blocks on the
// 128l x 256d tile (wave = 64l x 64d), gs2 stride 40 (af-read conflicts
// 2.94x -> 1.58x), ws stride 76, no async split.
// ---------------------------------------------------------------------------
template <bool PREW>
__global__ __launch_bounds__(512, 4) void pointwise_mfma(
    const unsigned short* __restrict__ g,  // (B,H,L) bf16 (workspace)
    const unsigned short* __restrict__ Wb, // (H,H) bf16 (workspace tail) if PREW
    const float* __restrict__ W,           // (H,H) fp32 row-major [d][c]
    const float* __restrict__ bias,        // (H) fp32
    float* __restrict__ out)               // (B,H,L) fp32
{
    __shared__ __align__(16) unsigned gs2[128 * 40];        // 20480 B
    __shared__ __align__(16) unsigned short ws[256 * 76];   // 38912 B

    const int tid = threadIdx.x;
    const int l0 = blockIdx.x * 128;
    const int d0 = blockIdx.y * 256;
    const int bz = blockIdx.z;
    const int w  = tid >> 6;
    const int lane = tid & 63;
    const int n  = lane & 15;      // MFMA row/col lane index
    const int q  = lane >> 4;      // quad
    const int wh = w & 1;          // l-half 0..1
    const int wd = w >> 1;         // d-quarter 0..3

    const int p   = tid & 31;      // c-pair column for g staging
    const int oct = (tid >> 5) & 7;// l-16-group 0..7 for g staging
    const int hi  = tid >> 8;      // staging split 0..1

    const int quarter = tid & 3;   // c-quarter for W staging
    const int rb      = (tid >> 2) & 63; // d-row base 0..63 for W staging

    floatx4 acc[4][4];
    #pragma unroll
    for (int mt = 0; mt < 4; mt++)
        #pragma unroll
        for (int nt = 0; nt < 4; nt++) acc[mt][nt] = (floatx4){0.f, 0.f, 0.f, 0.f};

    for (int c0 = 0; c0 < H_DIM; c0 += 64) {
        // ---- stage g tile (transpose-pack): rows c0+2p/+1, l = l0+16*oct+8*hi+0..7
        {
            const unsigned short* gp = g + ((size_t)bz * H_DIM + c0 + 2 * p) * L_DIM
                                         + l0 + 16 * oct + 8 * hi;
            uint4 va = *(const uint4*)gp;
            uint4 vb = *(const uint4*)(gp + L_DIM);
            const unsigned* ua = (const unsigned*)&va;
            const unsigned* ub = (const unsigned*)&vb;
            #pragma unroll
            for (int e = 0; e < 4; e++) {
                unsigned w0 = (ua[e] & 0xFFFFu) | (ub[e] << 16);        // l even
                unsigned w1 = (ua[e] >> 16) | (ub[e] & 0xFFFF0000u);    // l odd
                const int lrow = 16 * oct + 8 * hi + 2 * e;
                gs2[lrow * 40 + p] = w0;
                gs2[(lrow + 1) * 40 + p] = w1;
            }
        }
        // ---- stage W tile: rows rb + 64*(2*hi+g2), c = 16*quarter..+15
        if (PREW) {
            #pragma unroll
            for (int g2 = 0; g2 < 2; g2++) {
                const int row = rb + 64 * (2 * hi + g2);
                const unsigned short* wp = Wb + (size_t)(d0 + row) * H_DIM + c0 + 16 * quarter;
                uint4 w0 = ((const uint4*)wp)[0];
                uint4 w1 = ((const uint4*)wp)[1];
                *(uint4*)&ws[row * 76 + 16 * quarter]     = w0;
                *(uint4*)&ws[row * 76 + 16 * quarter + 8] = w1;
            }
        } else {
            #pragma unroll
            for (int g2 = 0; g2 < 2; g2++) {
                const int row = rb + 64 * (2 * hi + g2);
                const float* wp = W + (size_t)(d0 + row) * H_DIM + c0 + 16 * quarter;
                float4 f0 = ((const float4*)wp)[0];
                float4 f1 = ((const float4*)wp)[1];
                float4 f2 = ((const float4*)wp)[2];
                float4 f3 = ((const float4*)wp)[3];
                unsigned o0 = f2bf(f0.x) | (f2bf(f0.y) << 16);
                unsigned o1 = f2bf(f0.z) | (f2bf(f0.w) << 16);
                unsigned o2 = f2bf(f1.x) | (f2bf(f1.y) << 16);
                unsigned o3 = f2bf(f1.z) | (f2bf(f1.w) << 16);
                unsigned o4 = f2bf(f2.x) | (f2bf(f2.y) << 16);
                unsigned o5 = f2bf(f2.z) | (f2bf(f2.w) << 16);
                unsigned o6 = f2bf(f3.x) | (f2bf(f3.y) << 16);
                unsigned o7 = f2bf(f3.z) | (f2bf(f3.w) << 16);
                *(uint4*)&ws[row * 76 + 16 * quarter]     = make_uint4(o0, o1, o2, o3);
                *(uint4*)&ws[row * 76 + 16 * quarter + 8] = make_uint4(o4, o5, o6, o7);
            }
        }
        __syncthreads();

        // ---- compute: 2 K-steps of 32; per wave 4 mt x 4 nt MFMAs per step
        #pragma unroll
        for (int ks = 0; ks < 2; ks++) {
            short8 bfr[4];
            #pragma unroll
            for (int nt = 0; nt < 4; nt++)
                bfr[nt] = *(const short8*)&ws[(64 * wd + 16 * nt + n) * 76 + 32 * ks + 8 * q];
            #pragma unroll
            for (int mt = 0; mt < 4; mt++) {
                union { uint4 u4; short8 v; } af;
                af.u4 = *(const uint4*)&gs2[(64 * wh + 16 * mt + n) * 40 + 16 * ks + 4 * q];
                #pragma unroll
                for (int nt = 0; nt < 4; nt++)
                    acc[mt][nt] = __builtin_amdgcn_mfma_f32_16x16x32_bf16(af.v, bfr[nt], acc[mt][nt], 0, 0, 0);
            }
        }
        __syncthreads();
    }

    // ---- epilogue: bias + coalesced float4 stores (4 consecutive l per lane)
    #pragma unroll
    for (int nt = 0; nt < 4; nt++) {
        const int d = d0 + 64 * wd + 16 * nt + n;
        const float bb = bias[d];
        float* obase = out + ((size_t)bz * H_DIM + d) * L_DIM + l0 + 64 * wh + 4 * q;
        #pragma unroll
        for (int mt = 0; mt < 4; mt++) {
            float4 r = make_float4(acc[mt][nt][0] + bb, acc[mt][nt][1] + bb,
                                   acc[mt][nt][2] + bb, acc[mt][nt][3] + bb);
            *(float4*)(obase + 16 * mt) = r;
        }
    }
}

extern "C" void kernel_launch(void* const* d_in, const int* in_sizes, int n_in,
                              void* d_out, int out_size, void* d_ws, size_t ws_size,
                              hipStream_t stream) {
    const float* u    = (const float*)d_in[0]; // (B,H,L)
    const float* k    = (const float*)d_in[1]; // (C,H,L) C=1
    const float* D    = (const float*)d_in[2]; // (C,H)
    const float* W    = (const float*)d_in[3]; // (H,C*H)
    const float* bias = (const float*)d_in[4]; // (H)
    float* out = (float*)d_out;
    unsigned short* g = (unsigned short*)d_ws;  // (B,H,L) bf16 intermediate, 32 MiB

    const size_t g_bytes = (size_t)B_DIM * H_DIM * L_DIM * sizeof(unsigned short); // 32 MiB
    const size_t w_bytes = (size_t)H_DIM * H_DIM * sizeof(unsigned short);         // 512 KiB
    const bool prew = ws_size >= g_bytes + w_bytes;
    unsigned short* Wb = prew ? (unsigned short*)((char*)d_ws + g_bytes) : nullptr;

    conv_gelu_mfma<<<dim3(H_DIM, L_DIM / 1024), 512, 0, stream>>>(u, k, D, g, W, Wb);
    if (prew)
        pointwise_mfma<true><<<dim3(L_DIM / 128, H_DIM / 256, B_DIM), 512, 0, stream>>>(g, Wb, W, bias, out);
    else
        pointwise_mfma<false><<<dim3(L_DIM / 128, H_DIM / 256, B_DIM), 512, 0, stream>>>(g, nullptr, W, bias, out);
}

// Round 8
// 248.154 us; speedup vs baseline: 3.1880x; 1.0330x over previous
//
#include <hip/hip_runtime.h>
#include <hip/hip_bf16.h>
#include <math.h>

#define L_DIM 4096
#define H_DIM 512
#define B_DIM 8
#define SEG 2048

typedef __attribute__((ext_vector_type(8))) short short8;
typedef __attribute__((ext_vector_type(4))) float floatx4;

__device__ __forceinline__ unsigned f2bf(float f) {
    unsigned x = __float_as_uint(f);
    return (x + 0x7fffu + ((x >> 16) & 1u)) >> 16;   // RNE, finite inputs only
}

// ---------------------------------------------------------------------------
// Stage 1 (MFMA): causal Toeplitz conv + D-skip + exact GELU.
// Round-15: VERBATIM revert to the round-12 kernel (HW-verified 125us,
// VGPR 40, occ 47%). Round-14's T=4/SEG=1024 regressed to 147us: occupancy
// 75% but per-MFMA LDS+loop overhead doubled and FETCH went 58->143MB
// (4 l-chunks per h re-stage overlapping u windows). 24 waves/CU with the
// T=8 window is the verified optimum of this structure family.
// ---------------------------------------------------------------------------
__global__ __launch_bounds__(512, 6) void conv_gelu_mfma(
    const float* __restrict__ u,    // (B,H,L) fp32
    const float* __restrict__ kk,   // (C=1,H,L) fp32
    const float* __restrict__ Dp,   // (H) fp32
    unsigned short* __restrict__ g, // (B,H,L) bf16 out (workspace)
    const float* __restrict__ W,    // (H,H) fp32
    unsigned short* __restrict__ Wb)// (H,H) bf16 out (workspace tail), may be null
{
    __shared__ __align__(16) unsigned short kA[4144];
    __shared__ __align__(16) unsigned short kB[4144];
    __shared__ __align__(16) unsigned short us[8][2104];

    const int h   = blockIdx.x;
    const int Lb  = blockIdx.y << 11;        // l-chunk base (2048 per block)
    const int tid = threadIdx.x;
    const int lane = tid & 63;
    const int w   = tid >> 6;                // wave id 0..7
    const int i   = lane & 15;               // A-row / C-col index
    const int q   = lane >> 4;               // quad
    const int b   = i & 7;                   // batch   (C-col decode)
    const int s   = i >> 3;                  // l-tile  (C-col decode)

    // one-time W fp32 -> bf16 conversion (coalesced, one row per h-block)
    if (Wb != nullptr && blockIdx.y == 0) {
        const float* wsrc = W + (size_t)h * H_DIM;
        unsigned short* wdst = Wb + (size_t)h * H_DIM;
        wdst[tid] = (unsigned short)f2bf(wsrc[tid]);
    }

    const float* kh = kk + (size_t)h * L_DIM;

    for (int p = tid; p < 4144; p += 512) {
        int t1 = L_DIM + 15 - p;
        int t2 = L_DIM + 14 - p;
        float v1 = (t1 >= 0 && t1 < L_DIM) ? kh[t1] : 0.0f;
        float v2 = (t2 >= 0 && t2 < L_DIM) ? kh[t2] : 0.0f;
        kA[p] = (unsigned short)f2bf(v1);
        kB[p] = (unsigned short)f2bf(v2);
    }

    floatx4 acc[8];
    #pragma unroll
    for (int t = 0; t < 8; t++) acc[t] = (floatx4){0.f, 0.f, 0.f, 0.f};

    const char* kbase = (const char*)((i & 1) ? kA : kB);
    const int aconst = 2 * (L_DIM + ((i & 1) ? 15 : 14) - i + 8 * q);
    const int basew = Lb + 32 * w;           // l0(t) = basew + 256*t

    union AFrag { int x[4]; short8 v; };

    for (int seg = 0; seg < 2; seg++) {
        const int ms = seg * SEG;
        const int mstart = (seg == 0) ? -32 : SEG;
        const int segmax = ms + SEG - 32;
        if (seg == 1) {
            // max m0 any wave needs = basew_max + 256*7 = Lb + 2016
            if (Lb + 2016 < SEG) break;      // uniform per block
            __syncthreads();                 // protect us[] until seg-0 compute done
        }
        for (int e = tid * 4; e < 2096; e += 2048) {
            int m = ms - 32 + e;
            #pragma unroll
            for (int bb = 0; bb < 8; bb++) {
                float4 v = make_float4(0.f, 0.f, 0.f, 0.f);
                if (m >= 0 && m < L_DIM)
                    v = *(const float4*)(u + ((size_t)bb * H_DIM + h) * L_DIM + m);
                unsigned lo = f2bf(v.x) | (f2bf(v.y) << 16);
                unsigned hi = f2bf(v.z) | (f2bf(v.w) << 16);
                *(uint2*)&us[bb][e] = make_uint2(lo, hi);
            }
        }
        __syncthreads();

        const char* bbase = (const char*)&us[b][0] + 2 * (32 - ms + 16 * s + 8 * q);
        const char* ab = kbase + aconst;     // A-frag address at dd = 0

        for (int c = 0; c < 8; c++) {
            const int c32 = 32 * c;
            const int rel = basew - c32;
            // m0(j) = rel - 256*j must lie in [mstart, segmax]
            const int j_hi = (rel - mstart) >> 8;            // floor div
            int j_lo = (rel - segmax + 255) >> 8;            // ceil div
            if (j_lo < -7) j_lo = -7;                        // t<=7 bound
            if (j_hi < j_lo) continue;
            const int n = j_hi - j_lo + 1;

            AFrag Wd[8];
            // preload slots d=1..7: sigma = j_hi + d, dd = c32 + 256*sigma <= 4096
            #pragma unroll
            for (int d = 1; d < 8; d++) {
                const int dd = c32 + (j_hi + d) * 256;
                if (dd >= 0) {
                    const int* ap = (const int*)(ab - 2 * dd);
                    Wd[d].x[0] = ap[0]; Wd[d].x[1] = ap[1];
                    Wd[d].x[2] = ap[2]; Wd[d].x[3] = ap[3];
                } else {
                    Wd[d].x[0] = 0; Wd[d].x[1] = 0; Wd[d].x[2] = 0; Wd[d].x[3] = 0;
                }
            }

            const char* aab = ab - 2 * c32 - 512 * j_hi;     // +512*jj -> frag at j=j_hi-jj
            const char* bb0 = bbase + 2 * (rel - 256 * j_hi);// +512*jj -> B at m0(j)

            for (int jb = 0; jb < n; jb += 8) {
                #pragma unroll
                for (int k = 0; k < 8; k++) {
                    const int jj = jb + k;
                    if (jj < n) {
                        const int dd0 = c32 + (j_hi - jj) * 256;
                        AFrag nf;
                        if (dd0 >= 0) {
                            const int* ap = (const int*)(aab + 512 * jj);
                            nf.x[0] = ap[0]; nf.x[1] = ap[1];
                            nf.x[2] = ap[2]; nf.x[3] = ap[3];
                        } else {
                            // non-causal diagonal: zero frag -> MFMA adds 0
                            nf.x[0] = 0; nf.x[1] = 0; nf.x[2] = 0; nf.x[3] = 0;
                        }
                        Wd[(8 - k) & 7] = nf;                // slot (-jj)&7, static
                        short8 bf = *(const short8*)(bb0 + 512 * jj);
                        #pragma unroll
                        for (int t = 0; t < 8; t++)
                            acc[t] = __builtin_amdgcn_mfma_f32_16x16x32_bf16(
                                Wd[(t - k) & 7].v, bf, acc[t], 0, 0, 0);
                    }
                }
            }
        }
    }

    const float Dh = Dp[h];
    #pragma unroll
    for (int t = 0; t < 8; t++) {
        const int l0 = Lb + 32 * w + 256 * t;
        const int lb2 = l0 + 16 * s + 4 * q;          // C/D: row = 4q + r, col = (b,s)
        const size_t off = ((size_t)b * H_DIM + h) * L_DIM + lb2;
        float4 uv = *(const float4*)(u + off);
        float y0 = acc[t][0] + uv.x * Dh;
        float y1 = acc[t][1] + uv.y * Dh;
        float y2 = acc[t][2] + uv.z * Dh;
        float y3 = acc[t][3] + uv.w * Dh;
        const float c = 0.70710678118654752f;
        float g0 = 0.5f * y0 * (1.0f + erff(y0 * c));
        float g1 = 0.5f * y1 * (1.0f + erff(y1 * c));
        float g2 = 0.5f * y2 * (1.0f + erff(y2 * c));
        float g3 = 0.5f * y3 * (1.0f + erff(y3 * c));
        unsigned lo = f2bf(g0) | (f2bf(g1) << 16);
        unsigned hi = f2bf(g2) | (f2bf(g3) << 16);
        *(uint2*)(g + off) = make_uint2(lo, hi);
    }
}

// ---------------------------------------------------------------------------
// Stage 2 (MFMA v4): out[b,d,l] = sum_c W[d,c]*g[b,c,l] + bias[d], fp32 out.
// Round-15: true LDS double-buffer. All prior variants sat at ~104us =
// 250K cyc/CU, but MFMA+LDS+HBM account for <40% -- the unmodeled term is
// the lock-step {load -> barrier -> compute -> barrier} per c0-iter (only
// 8 iters, latency fully exposed). Double-buffer needs ONE barrier/iter:
// {issue loads(it+1); compute buf[cur]; write buf[cur^1]; sync} -- all
// hazard pairs barrier-separated (write(cur^1) vs prev-iter reads of
// cur^1: one sync between; compute(cur) vs prev write(cur): same sync).
// d-tile halved to 128 so 2 buffers fit 2 blocks/CU: LDS = 2*(20480+19456)
// = 79872 <= 80KB. Wave = 64l x 32d, acc 4x2. Grid x = d0 (fastest) so the
// 4 d0-blocks sharing a g-tile dispatch together -> L2/L3 locality.
// ---------------------------------------------------------------------------
template <bool PREW>
__global__ __launch_bounds__(512, 4) void pointwise_mfma(
    const unsigned short* __restrict__ g,  // (B,H,L) bf16 (workspace)
    const unsigned short* __restrict__ Wb, // (H,H) bf16 (workspace tail) if PREW
    const float* __restrict__ W,           // (H,H) fp32 row-major [d][c]
    const float* __restrict__ bias,        // (H) fp32
    float* __restrict__ out)               // (B,H,L) fp32
{
    __shared__ __align__(16) unsigned gs2[2][128 * 40];        // 2 x 20480 B
    __shared__ __align__(16) unsigned short ws[2][128 * 76];   // 2 x 19456 B

    const int tid = threadIdx.x;
    const int d0 = blockIdx.x * 128;
    const int l0 = blockIdx.y * 128;
    const int bz = blockIdx.z;
    const int w  = tid >> 6;
    const int lane = tid & 63;
    const int n  = lane & 15;      // MFMA row/col lane index
    const int q  = lane >> 4;      // quad
    const int wh = w & 1;          // l-half 0..1
    const int wd = w >> 1;         // d-quarter 0..3 (32 d each)

    const int p   = tid & 31;      // c-pair column for g staging
    const int oct = (tid >> 5) & 7;// l-16-group 0..7 for g staging
    const int hi  = tid >> 8;      // l-8-subgroup 0..1

    const int quarter = tid & 3;   // c-quarter for W staging
    const int rb      = tid >> 2;  // d-row 0..127 for W staging

    floatx4 acc[4][2];
    #pragma unroll
    for (int mt = 0; mt < 4; mt++)
        #pragma unroll
        for (int nt = 0; nt < 2; nt++) acc[mt][nt] = (floatx4){0.f, 0.f, 0.f, 0.f};

    const unsigned short* gbase = g + ((size_t)bz * H_DIM + 2 * p) * L_DIM + l0 + 16 * oct + 8 * hi;

    // staged-tile registers (live across compute for the prefetch overlap)
    uint4 ga, gb, wa, wb;

    // ---- load tile c0 into registers
    auto LOAD = [&](int c0) {
        const unsigned short* gp = gbase + (size_t)c0 * L_DIM;
        ga = *(const uint4*)gp;
        gb = *(const uint4*)(gp + L_DIM);
        if (PREW) {
            const unsigned short* wp = Wb + (size_t)(d0 + rb) * H_DIM + c0 + 16 * quarter;
            wa = ((const uint4*)wp)[0];
            wb = ((const uint4*)wp)[1];
        } else {
            const float* wp = W + (size_t)(d0 + rb) * H_DIM + c0 + 16 * quarter;
            float4 f0 = ((const float4*)wp)[0];
            float4 f1 = ((const float4*)wp)[1];
            float4 f2 = ((const float4*)wp)[2];
            float4 f3 = ((const float4*)wp)[3];
            wa = make_uint4(f2bf(f0.x) | (f2bf(f0.y) << 16), f2bf(f0.z) | (f2bf(f0.w) << 16),
                            f2bf(f1.x) | (f2bf(f1.y) << 16), f2bf(f1.z) | (f2bf(f1.w) << 16));
            wb = make_uint4(f2bf(f2.x) | (f2bf(f2.y) << 16), f2bf(f2.z) | (f2bf(f2.w) << 16),
                            f2bf(f3.x) | (f2bf(f3.y) << 16), f2bf(f3.z) | (f2bf(f3.w) << 16));
        }
    };
    // ---- write registers into LDS buffer bf
    auto WRITE = [&](int bf) {
        const unsigned* ua = (const unsigned*)&ga;
        const unsigned* ub = (const unsigned*)&gb;
        #pragma unroll
        for (int e = 0; e < 4; e++) {
            unsigned w0 = (ua[e] & 0xFFFFu) | (ub[e] << 16);        // l even
            unsigned w1 = (ua[e] >> 16) | (ub[e] & 0xFFFF0000u);    // l odd
            const int lrow = 16 * oct + 8 * hi + 2 * e;
            gs2[bf][lrow * 40 + p] = w0;
            gs2[bf][(lrow + 1) * 40 + p] = w1;
        }
        *(uint4*)&ws[bf][rb * 76 + 16 * quarter]     = wa;
        *(uint4*)&ws[bf][rb * 76 + 16 * quarter + 8] = wb;
    };

    LOAD(0);
    WRITE(0);
    __syncthreads();

    for (int it = 0; it < 8; it++) {
        const int cur = it & 1;
        if (it < 7) LOAD(64 * (it + 1));         // issue next tile's loads early
        // ---- compute on buf[cur]: 2 K-steps of 32; 4 mt x 2 nt MFMAs each
        #pragma unroll
        for (int ks = 0; ks < 2; ks++) {
            short8 bfr[2];
            #pragma unroll
            for (int nt = 0; nt < 2; nt++)
                bfr[nt] = *(const short8*)&ws[cur][(32 * wd + 16 * nt + n) * 76 + 32 * ks + 8 * q];
            #pragma unroll
            for (int mt = 0; mt < 4; mt++) {
                union { uint4 u4; short8 v; } af;
                af.u4 = *(const uint4*)&gs2[cur][(64 * wh + 16 * mt + n) * 40 + 16 * ks + 4 * q];
                #pragma unroll
                for (int nt = 0; nt < 2; nt++)
                    acc[mt][nt] = __builtin_amdgcn_mfma_f32_16x16x32_bf16(af.v, bfr[nt], acc[mt][nt], 0, 0, 0);
            }
        }
        if (it < 7) WRITE(cur ^ 1);              // land prefetched tile in other buffer
        __syncthreads();                         // single barrier per iteration
    }

    // ---- epilogue: bias + coalesced float4 stores (4 consecutive l per lane)
    #pragma unroll
    for (int nt = 0; nt < 2; nt++) {
        const int d = d0 + 32 * wd + 16 * nt + n;
        const float bb = bias[d];
        float* obase = out + ((size_t)bz * H_DIM + d) * L_DIM + l0 + 64 * wh + 4 * q;
        #pragma unroll
        for (int mt = 0; mt < 4; mt++) {
            float4 r = make_float4(acc[mt][nt][0] + bb, acc[mt][nt][1] + bb,
                                   acc[mt][nt][2] + bb, acc[mt][nt][3] + bb);
            *(float4*)(obase + 16 * mt) = r;
        }
    }
}

extern "C" void kernel_launch(void* const* d_in, const int* in_sizes, int n_in,
                              void* d_out, int out_size, void* d_ws, size_t ws_size,
                              hipStream_t stream) {
    const float* u    = (const float*)d_in[0]; // (B,H,L)
    const float* k    = (const float*)d_in[1]; // (C,H,L) C=1
    const float* D    = (const float*)d_in[2]; // (C,H)
    const float* W    = (const float*)d_in[3]; // (H,C*H)
    const float* bias = (const float*)d_in[4]; // (H)
    float* out = (float*)d_out;
    unsigned short* g = (unsigned short*)d_ws;  // (B,H,L) bf16 intermediate, 32 MiB

    const size_t g_bytes = (size_t)B_DIM * H_DIM * L_DIM * sizeof(unsigned short); // 32 MiB
    const size_t w_bytes = (size_t)H_DIM * H_DIM * sizeof(unsigned short);         // 512 KiB
    const bool prew = ws_size >= g_bytes + w_bytes;
    unsigned short* Wb = prew ? (unsigned short*)((char*)d_ws + g_bytes) : nullptr;

    conv_gelu_mfma<<<dim3(H_DIM, L_DIM / 2048), 512, 0, stream>>>(u, k, D, g, W, Wb);
    if (prew)
        pointwise_mfma<true><<<dim3(H_DIM / 128, L_DIM / 128, B_DIM), 512, 0, stream>>>(g, Wb, W, bias, out);
    else
        pointwise_mfma<false><<<dim3(H_DIM / 128, L_DIM / 128, B_DIM), 512, 0, stream>>>(g, nullptr, W, bias, out);
}

// Round 9
// 239.845 us; speedup vs baseline: 3.2985x; 1.0346x over previous
//
#include <hip/hip_runtime.h>
#include <hip/hip_bf16.h>
#include <math.h>

#define L_DIM 4096
#define H_DIM 512
#define B_DIM 8
#define SEG 2048

typedef __attribute__((ext_vector_type(8))) short short8;
typedef __attribute__((ext_vector_type(4))) float floatx4;

__device__ __forceinline__ unsigned f2bf(float f) {
    unsigned x = __float_as_uint(f);
    return (x + 0x7fffu + ((x >> 16) & 1u)) >> 16;   // RNE, finite inputs only
}

// ---------------------------------------------------------------------------
// Stage 1 (MFMA): causal Toeplitz conv + D-skip + exact GELU.
// UNCHANGED from round-15 (HW-verified 125us, VGPR 40) except the Wb writer
// now emits a FRAG-MAJOR bf16 W layout for stage 2:
//   Wb2 idx(d=h, c) = (((d>>4)*64 + (c>>3))*16 + (d&15))*8 + (c&7)
// so a stage-2 wave's B-frag load is lane-contiguous (lane n reads 16B at
// n*16B within a 256B frag block) -> fully coalesced, no LDS round-trip.
// ---------------------------------------------------------------------------
__global__ __launch_bounds__(512, 6) void conv_gelu_mfma(
    const float* __restrict__ u,    // (B,H,L) fp32
    const float* __restrict__ kk,   // (C=1,H,L) fp32
    const float* __restrict__ Dp,   // (H) fp32
    unsigned short* __restrict__ g, // (B,H,L) bf16 out (workspace)
    const float* __restrict__ W,    // (H,H) fp32
    unsigned short* __restrict__ Wb)// (H,H) bf16 frag-major (workspace tail), may be null
{
    __shared__ __align__(16) unsigned short kA[4144];
    __shared__ __align__(16) unsigned short kB[4144];
    __shared__ __align__(16) unsigned short us[8][2104];

    const int h   = blockIdx.x;
    const int Lb  = blockIdx.y << 11;        // l-chunk base (2048 per block)
    const int tid = threadIdx.x;
    const int lane = tid & 63;
    const int w   = tid >> 6;                // wave id 0..7
    const int i   = lane & 15;               // A-row / C-col index
    const int q   = lane >> 4;               // quad
    const int b   = i & 7;                   // batch   (C-col decode)
    const int s   = i >> 3;                  // l-tile  (C-col decode)

    // one-time W fp32 -> bf16 frag-major conversion (one row per h-block)
    if (Wb != nullptr && blockIdx.y == 0) {
        const float* wsrc = W + (size_t)h * H_DIM;
        const int c = tid;                   // 512 threads == H_DIM
        const int idx = (((h >> 4) * 64 + (c >> 3)) * 16 + (h & 15)) * 8 + (c & 7);
        Wb[idx] = (unsigned short)f2bf(wsrc[c]);
    }

    const float* kh = kk + (size_t)h * L_DIM;

    for (int p = tid; p < 4144; p += 512) {
        int t1 = L_DIM + 15 - p;
        int t2 = L_DIM + 14 - p;
        float v1 = (t1 >= 0 && t1 < L_DIM) ? kh[t1] : 0.0f;
        float v2 = (t2 >= 0 && t2 < L_DIM) ? kh[t2] : 0.0f;
        kA[p] = (unsigned short)f2bf(v1);
        kB[p] = (unsigned short)f2bf(v2);
    }

    floatx4 acc[8];
    #pragma unroll
    for (int t = 0; t < 8; t++) acc[t] = (floatx4){0.f, 0.f, 0.f, 0.f};

    const char* kbase = (const char*)((i & 1) ? kA : kB);
    const int aconst = 2 * (L_DIM + ((i & 1) ? 15 : 14) - i + 8 * q);
    const int basew = Lb + 32 * w;           // l0(t) = basew + 256*t

    union AFrag { int x[4]; short8 v; };

    for (int seg = 0; seg < 2; seg++) {
        const int ms = seg * SEG;
        const int mstart = (seg == 0) ? -32 : SEG;
        const int segmax = ms + SEG - 32;
        if (seg == 1) {
            // max m0 any wave needs = basew_max + 256*7 = Lb + 2016
            if (Lb + 2016 < SEG) break;      // uniform per block
            __syncthreads();                 // protect us[] until seg-0 compute done
        }
        for (int e = tid * 4; e < 2096; e += 2048) {
            int m = ms - 32 + e;
            #pragma unroll
            for (int bb = 0; bb < 8; bb++) {
                float4 v = make_float4(0.f, 0.f, 0.f, 0.f);
                if (m >= 0 && m < L_DIM)
                    v = *(const float4*)(u + ((size_t)bb * H_DIM + h) * L_DIM + m);
                unsigned lo = f2bf(v.x) | (f2bf(v.y) << 16);
                unsigned hi = f2bf(v.z) | (f2bf(v.w) << 16);
                *(uint2*)&us[bb][e] = make_uint2(lo, hi);
            }
        }
        __syncthreads();

        const char* bbase = (const char*)&us[b][0] + 2 * (32 - ms + 16 * s + 8 * q);
        const char* ab = kbase + aconst;     // A-frag address at dd = 0

        for (int c = 0; c < 8; c++) {
            const int c32 = 32 * c;
            const int rel = basew - c32;
            // m0(j) = rel - 256*j must lie in [mstart, segmax]
            const int j_hi = (rel - mstart) >> 8;            // floor div
            int j_lo = (rel - segmax + 255) >> 8;            // ceil div
            if (j_lo < -7) j_lo = -7;                        // t<=7 bound
            if (j_hi < j_lo) continue;
            const int n = j_hi - j_lo + 1;

            AFrag Wd[8];
            // preload slots d=1..7: sigma = j_hi + d, dd = c32 + 256*sigma <= 4096
            #pragma unroll
            for (int d = 1; d < 8; d++) {
                const int dd = c32 + (j_hi + d) * 256;
                if (dd >= 0) {
                    const int* ap = (const int*)(ab - 2 * dd);
                    Wd[d].x[0] = ap[0]; Wd[d].x[1] = ap[1];
                    Wd[d].x[2] = ap[2]; Wd[d].x[3] = ap[3];
                } else {
                    Wd[d].x[0] = 0; Wd[d].x[1] = 0; Wd[d].x[2] = 0; Wd[d].x[3] = 0;
                }
            }

            const char* aab = ab - 2 * c32 - 512 * j_hi;     // +512*jj -> frag at j=j_hi-jj
            const char* bb0 = bbase + 2 * (rel - 256 * j_hi);// +512*jj -> B at m0(j)

            for (int jb = 0; jb < n; jb += 8) {
                #pragma unroll
                for (int k = 0; k < 8; k++) {
                    const int jj = jb + k;
                    if (jj < n) {
                        const int dd0 = c32 + (j_hi - jj) * 256;
                        AFrag nf;
                        if (dd0 >= 0) {
                            const int* ap = (const int*)(aab + 512 * jj);
                            nf.x[0] = ap[0]; nf.x[1] = ap[1];
                            nf.x[2] = ap[2]; nf.x[3] = ap[3];
                        } else {
                            // non-causal diagonal: zero frag -> MFMA adds 0
                            nf.x[0] = 0; nf.x[1] = 0; nf.x[2] = 0; nf.x[3] = 0;
                        }
                        Wd[(8 - k) & 7] = nf;                // slot (-jj)&7, static
                        short8 bf = *(const short8*)(bb0 + 512 * jj);
                        #pragma unroll
                        for (int t = 0; t < 8; t++)
                            acc[t] = __builtin_amdgcn_mfma_f32_16x16x32_bf16(
                                Wd[(t - k) & 7].v, bf, acc[t], 0, 0, 0);
                    }
                }
            }
        }
    }

    const float Dh = Dp[h];
    #pragma unroll
    for (int t = 0; t < 8; t++) {
        const int l0 = Lb + 32 * w + 256 * t;
        const int lb2 = l0 + 16 * s + 4 * q;          // C/D: row = 4q + r, col = (b,s)
        const size_t off = ((size_t)b * H_DIM + h) * L_DIM + lb2;
        float4 uv = *(const float4*)(u + off);
        float y0 = acc[t][0] + uv.x * Dh;
        float y1 = acc[t][1] + uv.y * Dh;
        float y2 = acc[t][2] + uv.z * Dh;
        float y3 = acc[t][3] + uv.w * Dh;
        const float c = 0.70710678118654752f;
        float g0 = 0.5f * y0 * (1.0f + erff(y0 * c));
        float g1 = 0.5f * y1 * (1.0f + erff(y1 * c));
        float g2 = 0.5f * y2 * (1.0f + erff(y2 * c));
        float g3 = 0.5f * y3 * (1.0f + erff(y3 * c));
        unsigned lo = f2bf(g0) | (f2bf(g1) << 16);
        unsigned hi = f2bf(g2) | (f2bf(g3) << 16);
        *(uint2*)(g + off) = make_uint2(lo, hi);
    }
}

// ---------------------------------------------------------------------------
// Stage 2 (MFMA v5): out[b,d,l] = sum_c W[d,c]*g[b,c,l] + bias[d], fp32 out.
// Round-16: big-tile dbuf + W-in-registers. Round-8 showed dbuf on a small
// tile loses (pack volume doubles); round-6's 104us is 2% MFMA-bound --
// mostly exposed latency + the ws LDS round-trip. New: 256l x 256d tile,
// 1024 threads (16 waves, 4 wl x 4 wd of 64l x 64d), gs2-only double
// buffer (2 x 40KB = 80KB, 1 block/CU, grid 256 = exactly 1/CU). W-frags
// come straight from the frag-major Wb2 (lane-contiguous 256B runs, L2-
// resident) -- ws buffer, its writes and b128 reads deleted. One barrier
// per c0-iter; next g-tile issued before compute. VGPR ~105 <= 128 cap.
// ---------------------------------------------------------------------------
template <bool PREW>
__global__ __launch_bounds__(1024, 4) void pointwise_mfma(
    const unsigned short* __restrict__ g,  // (B,H,L) bf16 (workspace)
    const unsigned short* __restrict__ Wb, // (H,H) bf16 frag-major if PREW
    const float* __restrict__ W,           // (H,H) fp32 row-major [d][c]
    const float* __restrict__ bias,        // (H) fp32
    float* __restrict__ out)               // (B,H,L) fp32
{
    __shared__ __align__(16) unsigned gs2[2][256 * 40];     // 2 x 40960 B

    const int tid = threadIdx.x;
    const int d0 = blockIdx.x * 256;
    const int l0 = blockIdx.y * 256;
    const int bz = blockIdx.z;
    const int w  = tid >> 6;
    const int lane = tid & 63;
    const int n  = lane & 15;      // MFMA row/col lane index
    const int q  = lane >> 4;      // quad
    const int wl = w >> 2;         // l-quarter 0..3 (64 l each)
    const int wd = w & 3;          // d-quarter 0..3 (64 d each)

    const int p   = tid & 31;      // c-pair column for g staging
    const int grp = tid >> 5;      // l-8-group 0..31 for g staging

    floatx4 acc[4][4];
    #pragma unroll
    for (int mt = 0; mt < 4; mt++)
        #pragma unroll
        for (int nt = 0; nt < 4; nt++) acc[mt][nt] = (floatx4){0.f, 0.f, 0.f, 0.f};

    const unsigned short* gbase = g + ((size_t)bz * H_DIM + 2 * p) * L_DIM + l0 + 8 * grp;

    uint4 ga, gb;   // staged g rows (live across compute for prefetch overlap)

    auto LOAD = [&](int c0) {
        const unsigned short* gp = gbase + (size_t)c0 * L_DIM;
        ga = *(const uint4*)gp;           // row c0+2p,   8 l
        gb = *(const uint4*)(gp + L_DIM); // row c0+2p+1, 8 l
    };
    auto WRITE = [&](int bf) {
        const unsigned* ua = (const unsigned*)&ga;
        const unsigned* ub = (const unsigned*)&gb;
        #pragma unroll
        for (int e = 0; e < 4; e++) {
            unsigned w0 = (ua[e] & 0xFFFFu) | (ub[e] << 16);        // l even
            unsigned w1 = (ua[e] >> 16) | (ub[e] & 0xFFFF0000u);    // l odd
            const int lrow = 8 * grp + 2 * e;
            gs2[bf][lrow * 40 + p] = w0;
            gs2[bf][(lrow + 1) * 40 + p] = w1;
        }
    };

    LOAD(0);
    WRITE(0);
    __syncthreads();

    for (int it = 0; it < 8; it++) {
        const int cur = it & 1;
        const int c0 = 64 * it;
        if (it < 7) LOAD(64 * (it + 1));         // issue next tile's loads early

        // ---- compute on gs2[cur]: 2 K-steps of 32; 4 mt x 4 nt MFMAs each
        #pragma unroll
        for (int ks = 0; ks < 2; ks++) {
            short8 bw[4];                         // W B-frags, straight from global
            #pragma unroll
            for (int nt = 0; nt < 4; nt++) {
                if (PREW) {
                    // frag-major: lane n reads 16B at n*16B -> contiguous 256B
                    const unsigned short* wp = Wb +
                        ((((size_t)(d0 >> 4) + 4 * wd + nt) * 64 + (c0 >> 3) + 4 * ks + q) * 16 + n) * 8;
                    bw[nt] = *(const short8*)wp;
                } else {
                    const int d = d0 + 64 * wd + 16 * nt + n;
                    const float* wp = W + (size_t)d * H_DIM + c0 + 32 * ks + 8 * q;
                    float4 f0 = ((const float4*)wp)[0];
                    float4 f1 = ((const float4*)wp)[1];
                    union { unsigned u[4]; short8 v; } pk;
                    pk.u[0] = f2bf(f0.x) | (f2bf(f0.y) << 16);
                    pk.u[1] = f2bf(f0.z) | (f2bf(f0.w) << 16);
                    pk.u[2] = f2bf(f1.x) | (f2bf(f1.y) << 16);
                    pk.u[3] = f2bf(f1.z) | (f2bf(f1.w) << 16);
                    bw[nt] = pk.v;
                }
            }
            #pragma unroll
            for (int mt = 0; mt < 4; mt++) {
                union { uint4 u4; short8 v; } af;
                af.u4 = *(const uint4*)&gs2[cur][(64 * wl + 16 * mt + n) * 40 + 16 * ks + 4 * q];
                #pragma unroll
                for (int nt = 0; nt < 4; nt++)
                    acc[mt][nt] = __builtin_amdgcn_mfma_f32_16x16x32_bf16(af.v, bw[nt], acc[mt][nt], 0, 0, 0);
            }
        }

        if (it < 7) WRITE(cur ^ 1);              // land prefetched tile in other buffer
        __syncthreads();                         // single barrier per iteration
    }

    // ---- epilogue: bias + coalesced float4 stores (4 consecutive l per lane)
    #pragma unroll
    for (int nt = 0; nt < 4; nt++) {
        const int d = d0 + 64 * wd + 16 * nt + n;
        const float bb = bias[d];
        float* obase = out + ((size_t)bz * H_DIM + d) * L_DIM + l0 + 64 * wl + 4 * q;
        #pragma unroll
        for (int mt = 0; mt < 4; mt++) {
            float4 r = make_float4(acc[mt][nt][0] + bb, acc[mt][nt][1] + bb,
                                   acc[mt][nt][2] + bb, acc[mt][nt][3] + bb);
            *(float4*)(obase + 16 * mt) = r;
        }
    }
}

extern "C" void kernel_launch(void* const* d_in, const int* in_sizes, int n_in,
                              void* d_out, int out_size, void* d_ws, size_t ws_size,
                              hipStream_t stream) {
    const float* u    = (const float*)d_in[0]; // (B,H,L)
    const float* k    = (const float*)d_in[1]; // (C,H,L) C=1
    const float* D    = (const float*)d_in[2]; // (C,H)
    const float* W    = (const float*)d_in[3]; // (H,C*H)
    const float* bias = (const float*)d_in[4]; // (H)
    float* out = (float*)d_out;
    unsigned short* g = (unsigned short*)d_ws;  // (B,H,L) bf16 intermediate, 32 MiB

    const size_t g_bytes = (size_t)B_DIM * H_DIM * L_DIM * sizeof(unsigned short); // 32 MiB
    const size_t w_bytes = (size_t)H_DIM * H_DIM * sizeof(unsigned short);         // 512 KiB
    const bool prew = ws_size >= g_bytes + w_bytes;
    unsigned short* Wb = prew ? (unsigned short*)((char*)d_ws + g_bytes) : nullptr;

    conv_gelu_mfma<<<dim3(H_DIM, L_DIM / 2048), 512, 0, stream>>>(u, k, D, g, W, Wb);
    if (prew)
        pointwise_mfma<true><<<dim3(H_DIM / 256, L_DIM / 256, B_DIM), 1024, 0, stream>>>(g, Wb, W, bias, out);
    else
        pointwise_mfma<false><<<dim3(H_DIM / 256, L_DIM / 256, B_DIM), 1024, 0, stream>>>(g, nullptr, W, bias, out);
}